// Round 3
// baseline (937.401 us; speedup 1.0000x reference)
//
#include <hip/hip_runtime.h>
#include <stdint.h>

#define RESO 192
#define DATA_DIM 28
#define CHUNKS 7     // DATA_DIM / 4
#define TILE 32      // cells per tile edge -> 33^3 nodes ~ 4.0 MB data (L2-sized)
#define TPA 6        // tiles per axis (192/32)
#define NT 216       // TPA^3
#define NXCD 8
#define TPX 27       // tiles per XCD (216/8)

// ---------------- helpers ----------------

__device__ __forceinline__ float4 f4_lerp(float4 a, float4 b, float wa, float wb) {
    float4 r;
    r.x = fmaf(a.x, wa, b.x * wb);
    r.y = fmaf(a.y, wa, b.y * wb);
    r.z = fmaf(a.z, wa, b.z * wb);
    r.w = fmaf(a.w, wa, b.w * wb);
    return r;
}

// ---------------- pipeline kernels ----------------

__global__ void k_zero(int* __restrict__ hist) {
    int i = threadIdx.x;
    if (i < NT) hist[i] = 0;
}

__global__ __launch_bounds__(256) void k_prep(
    const float* __restrict__ points,
    const float* __restrict__ offset,
    const float* __restrict__ scaling,
    int* __restrict__ hist,
    uint8_t* __restrict__ key8,
    int n)
{
    __shared__ int h[NT];
    for (int i = threadIdx.x; i < NT; i += 256) h[i] = 0;
    __syncthreads();
    const int p = blockIdx.x * 256 + threadIdx.x;
    if (p < n) {
        int t = 0;
#pragma unroll
        for (int i = 0; i < 3; ++i) {
            float v = fmaf(points[(size_t)p * 3 + i], scaling[i] * (float)RESO,
                           offset[i] * (float)RESO - 0.5f);
            v = fminf(fmaxf(v, 0.0f), (float)RESO - 1.0f);
            int li = (int)v;
            if (li > RESO - 2) li = RESO - 2;
            t = t * TPA + (li >> 5);   // TILE = 32
        }
        key8[p] = (uint8_t)t;
        atomicAdd(&h[t], 1);
    }
    __syncthreads();
    for (int i = threadIdx.x; i < NT; i += 256)
        if (h[i]) atomicAdd(&hist[i], h[i]);
}

__global__ void k_scan(const int* __restrict__ hist,
                       int* __restrict__ csum,
                       int* __restrict__ cursor)
{
    if (threadIdx.x == 0) {
        int run = 0;
        for (int s = 0; s < NT; ++s) { csum[s] = run; cursor[s] = run; run += hist[s]; }
        csum[NT] = run;
    }
}

__global__ __launch_bounds__(256) void k_scatter(
    const float* __restrict__ points,
    const float* __restrict__ offset,
    const float* __restrict__ scaling,
    const uint8_t* __restrict__ key8,
    int* __restrict__ cursor,
    int* __restrict__ perm,
    float4* __restrict__ pre4,
    int n)
{
    __shared__ int h[NT];
    __shared__ int basev[NT];
    for (int i = threadIdx.x; i < NT; i += 256) h[i] = 0;
    __syncthreads();
    const int p = blockIdx.x * 256 + threadIdx.x;
    int key = 0, local = 0;
    const bool valid = (p < n);
    if (valid) { key = key8[p]; local = atomicAdd(&h[key], 1); }
    __syncthreads();
    for (int i = threadIdx.x; i < NT; i += 256) {
        const int c = h[i];
        basev[i] = c ? atomicAdd(&cursor[i], c) : 0;
    }
    __syncthreads();
    if (valid) {
        float wbv[3];
        int   l[3];
#pragma unroll
        for (int i = 0; i < 3; ++i) {
            float v = fmaf(points[(size_t)p * 3 + i], scaling[i] * (float)RESO,
                           offset[i] * (float)RESO - 0.5f);
            v = fminf(fmaxf(v, 0.0f), (float)RESO - 1.0f);
            int li = (int)v;
            if (li > RESO - 2) li = RESO - 2;
            l[i] = li;
            wbv[i] = v - (float)li;
        }
        const int gbase = (l[0] * RESO + l[1]) * RESO + l[2];
        const int slot = basev[key] + local;
        perm[slot] = p;
        pre4[slot] = make_float4(wbv[0], wbv[1], wbv[2], __int_as_float(gbase));
    }
}

// ---------------- main sampling kernel (persistent, XCD-pinned) ----------------

__global__ __launch_bounds__(256) void k_sample_sorted(
    const float4* __restrict__ pre4,
    const int*    __restrict__ perm,
    const int*    __restrict__ csum,
    const float*  __restrict__ data,
    const int*    __restrict__ links,
    float*        __restrict__ out)
{
    const int b = blockIdx.x;
    const int k = b & (NXCD - 1);      // XCD id (round-robin dispatch)
    const int j = b >> 3;              // block index within XCD, [0,256)
    const int lo = csum[k * TPX];
    const int hi = csum[(k + 1) * TPX];
    const int nwork = (hi - lo) * CHUNKS;

    for (int item = j * 256 + (int)threadIdx.x; item < nwork; item += 256 * 256) {
        const int slot = lo + item / CHUNKS;
        const int c    = item % CHUNKS;

        const float4 pw = pre4[slot];     // 7 lanes same addr -> broadcast
        const int    p  = perm[slot];
        const int gbase = __float_as_int(pw.w);

        const int dz = 1, dy = RESO, dx = RESO * RESO;
        int lk[8];
        lk[0] = links[gbase];
        lk[1] = links[gbase + dz];
        lk[2] = links[gbase + dy];
        lk[3] = links[gbase + dy + dz];
        lk[4] = links[gbase + dx];
        lk[5] = links[gbase + dx + dz];
        lk[6] = links[gbase + dx + dy];
        lk[7] = links[gbase + dx + dy + dz];

        float4 cv[8];
#pragma unroll
        for (int q = 0; q < 8; ++q) {
            const int idx = lk[q] < 0 ? 0 : lk[q];
            cv[q] = *reinterpret_cast<const float4*>(
                data + (size_t)idx * DATA_DIM + (size_t)c * 4);
        }
#pragma unroll
        for (int q = 0; q < 8; ++q) {
            if (lk[q] < 0) cv[q] = make_float4(0.f, 0.f, 0.f, 0.f);
        }

        const float waz = 1.0f - pw.z, wbz = pw.z;
        const float way = 1.0f - pw.y, wby = pw.y;
        const float wax = 1.0f - pw.x, wbx = pw.x;

        float4 c00 = f4_lerp(cv[0], cv[1], waz, wbz);
        float4 c01 = f4_lerp(cv[2], cv[3], waz, wbz);
        float4 c10 = f4_lerp(cv[4], cv[5], waz, wbz);
        float4 c11 = f4_lerp(cv[6], cv[7], waz, wbz);

        float4 c0 = f4_lerp(c00, c01, way, wby);
        float4 c1 = f4_lerp(c10, c11, way, wby);
        float4 s  = f4_lerp(c0, c1, wax, wbx);

        *reinterpret_cast<float4*>(out + (size_t)p * DATA_DIM + (size_t)c * 4) = s;
    }
}

// ---------------- fallback (direct order) ----------------

__global__ __launch_bounds__(256) void k_sample_direct(
    const float* __restrict__ points,
    const float* __restrict__ data,
    const int*   __restrict__ links,
    const float* __restrict__ offset,
    const float* __restrict__ scaling,
    float*       __restrict__ out,
    int n_pts)
{
    const int tid = blockIdx.x * blockDim.x + threadIdx.x;
    const int total = n_pts * CHUNKS;
    if (tid >= total) return;

    const int p = tid / CHUNKS;
    const int c = tid - p * CHUNKS;

    int   l[3];
    float wb[3];
#pragma unroll
    for (int i = 0; i < 3; ++i) {
        float v = fmaf(points[(size_t)p * 3 + i], scaling[i] * (float)RESO,
                       offset[i] * (float)RESO - 0.5f);
        v = fminf(fmaxf(v, 0.0f), (float)RESO - 1.0f);
        int li = (int)v;
        li = li < 0 ? 0 : (li > RESO - 2 ? RESO - 2 : li);
        l[i] = li;
        wb[i] = v - (float)li;
    }

    const int dz = 1, dy = RESO, dx = RESO * RESO;
    const int base = (l[0] * RESO + l[1]) * RESO + l[2];

    int lk[8];
    lk[0] = links[base];
    lk[1] = links[base + dz];
    lk[2] = links[base + dy];
    lk[3] = links[base + dy + dz];
    lk[4] = links[base + dx];
    lk[5] = links[base + dx + dz];
    lk[6] = links[base + dx + dy];
    lk[7] = links[base + dx + dy + dz];

    float4 cv[8];
#pragma unroll
    for (int q = 0; q < 8; ++q) {
        const int idx = lk[q] < 0 ? 0 : lk[q];
        cv[q] = *reinterpret_cast<const float4*>(
            data + (size_t)idx * DATA_DIM + (size_t)c * 4);
    }
#pragma unroll
    for (int q = 0; q < 8; ++q) {
        if (lk[q] < 0) cv[q] = make_float4(0.f, 0.f, 0.f, 0.f);
    }

    const float waz = 1.0f - wb[2], wbz = wb[2];
    const float way = 1.0f - wb[1], wby = wb[1];
    const float wax = 1.0f - wb[0], wbx = wb[0];

    float4 c00 = f4_lerp(cv[0], cv[1], waz, wbz);
    float4 c01 = f4_lerp(cv[2], cv[3], waz, wbz);
    float4 c10 = f4_lerp(cv[4], cv[5], waz, wbz);
    float4 c11 = f4_lerp(cv[6], cv[7], waz, wbz);

    float4 c0 = f4_lerp(c00, c01, way, wby);
    float4 c1 = f4_lerp(c10, c11, way, wby);
    float4 s  = f4_lerp(c0, c1, wax, wbx);

    *reinterpret_cast<float4*>(out + (size_t)tid * 4) = s;
}

// ---------------- launch ----------------

extern "C" void kernel_launch(void* const* d_in, const int* in_sizes, int n_in,
                              void* d_out, int out_size, void* d_ws, size_t ws_size,
                              hipStream_t stream)
{
    const float* points  = (const float*)d_in[0];
    const float* data    = (const float*)d_in[1];
    const int*   links   = (const int*)d_in[2];
    const float* offset  = (const float*)d_in[3];
    const float* scaling = (const float*)d_in[4];
    float*       out     = (float*)d_out;

    const int n_pts = in_sizes[0] / 3;
    const int block = 256;

    // ws layout (all 16B-aligned):
    //   hist[NT] | csum[NT+1] | cursor[NT] | key8[n] | perm[n] | pre4[n]
    size_t off = 0;
    auto alloc = [&](size_t bytes) {
        size_t a = off;
        off = (off + bytes + 15) & ~(size_t)15;
        return a;
    };
    const size_t o_hist   = alloc(NT * 4);
    const size_t o_csum   = alloc((NT + 1) * 4);
    const size_t o_cursor = alloc(NT * 4);
    const size_t o_key8   = alloc((size_t)n_pts);
    const size_t o_perm   = alloc((size_t)n_pts * 4);
    const size_t o_pre4   = alloc((size_t)n_pts * 16);
    const size_t need = off;

    if (ws_size >= need) {
        int*     hist   = (int*)((char*)d_ws + o_hist);
        int*     csum   = (int*)((char*)d_ws + o_csum);
        int*     cursor = (int*)((char*)d_ws + o_cursor);
        uint8_t* key8   = (uint8_t*)((char*)d_ws + o_key8);
        int*     perm   = (int*)((char*)d_ws + o_perm);
        float4*  pre4   = (float4*)((char*)d_ws + o_pre4);

        const int gpts = (n_pts + block - 1) / block;

        k_zero<<<1, 256, 0, stream>>>(hist);
        k_prep<<<gpts, block, 0, stream>>>(points, offset, scaling, hist, key8, n_pts);
        k_scan<<<1, 64, 0, stream>>>(hist, csum, cursor);
        k_scatter<<<gpts, block, 0, stream>>>(points, offset, scaling, key8,
                                              cursor, perm, pre4, n_pts);
        k_sample_sorted<<<2048, block, 0, stream>>>(pre4, perm, csum, data, links, out);
    } else {
        const int total = n_pts * CHUNKS;
        k_sample_direct<<<(total + block - 1) / block, block, 0, stream>>>(
            points, data, links, offset, scaling, out, n_pts);
    }
}

// Round 4
// 580.781 us; speedup vs baseline: 1.6140x; 1.6140x over previous
//
#include <hip/hip_runtime.h>
#include <stdint.h>

#define RESO 192
#define DATA_DIM 28
#define CHUNKS 7        // DATA_DIM / 4
#define TPA 12          // tiles per axis (tile = 16 cells)
#define NT 1728         // TPA^3 bins
#define NXCD 8
#define TPX 216         // NT / NXCD  -> contiguous x-slab of 24 cells per XCD
#define BLOCKS_P 256    // histogram / scatter blocks
#define SAMPLE_BLOCKS 1024  // 128 blocks/XCD -> per-XCD window ~4.7K pts ~2.2MB (L2-fit)

// ---------------- shared device helpers ----------------

__device__ __forceinline__ float4 f4_lerp(float4 a, float4 b, float wa, float wb) {
    float4 r;
    r.x = fmaf(a.x, wa, b.x * wb);
    r.y = fmaf(a.y, wa, b.y * wb);
    r.z = fmaf(a.z, wa, b.z * wb);
    r.w = fmaf(a.w, wa, b.w * wb);
    return r;
}

// coordinate transform for one point; returns tile key, fills l[3], wb[3]
__device__ __forceinline__ int point_coords(
    const float* __restrict__ points,
    const float* __restrict__ offset,
    const float* __restrict__ scaling,
    int p, int* l, float* wb)
{
    int t = 0;
#pragma unroll
    for (int i = 0; i < 3; ++i) {
        float v = fmaf(points[(size_t)p * 3 + i], scaling[i] * (float)RESO,
                       offset[i] * (float)RESO - 0.5f);
        v = fminf(fmaxf(v, 0.0f), (float)RESO - 1.0f);
        int li = (int)v;                 // v >= 0 -> trunc == floor
        if (li > RESO - 2) li = RESO - 2;
        l[i] = li;
        wb[i] = v - (float)li;
        t = t * TPA + (li >> 4);         // tile = 16 cells
    }
    return t;
}

// ---------------- sort pipeline (atomic-free at global scope) ----------------

__global__ __launch_bounds__(256) void k_hist(
    const float* __restrict__ points,
    const float* __restrict__ offset,
    const float* __restrict__ scaling,
    int* __restrict__ ghist,   // [NT][BLOCKS_P]
    int n, int ppb)
{
    __shared__ int lh[NT];
    for (int i = threadIdx.x; i < NT; i += 256) lh[i] = 0;
    __syncthreads();
    const int b = blockIdx.x;
    const int lo = b * ppb;
    const int hi = min(lo + ppb, n);
    for (int p = lo + threadIdx.x; p < hi; p += 256) {
        int l[3]; float wb[3];
        const int t = point_coords(points, offset, scaling, p, l, wb);
        atomicAdd(&lh[t], 1);
    }
    __syncthreads();
    for (int i = threadIdx.x; i < NT; i += 256)
        ghist[(size_t)i * BLOCKS_P + b] = lh[i];
}

__global__ __launch_bounds__(1024) void k_scan_bins(
    const int* __restrict__ ghist,  // [NT][BLOCKS_P]
    int* __restrict__ csum)         // [NT+1] exclusive bin starts
{
    __shared__ int buf[2][2048];
    for (int t = threadIdx.x; t < 2048; t += 1024) {
        int s = 0;
        if (t < NT) {
            const int* row = ghist + (size_t)t * BLOCKS_P;
            for (int b = 0; b < BLOCKS_P; ++b) s += row[b];
        }
        buf[0][t] = s;
    }
    __syncthreads();
    int src = 0;
    for (int d = 1; d < 2048; d <<= 1) {
        for (int t = threadIdx.x; t < 2048; t += 1024)
            buf[src ^ 1][t] = buf[src][t] + (t >= d ? buf[src][t - d] : 0);
        __syncthreads();
        src ^= 1;
    }
    for (int t = threadIdx.x; t < NT; t += 1024)
        csum[t] = t ? buf[src][t - 1] : 0;
    if (threadIdx.x == 0) csum[NT] = buf[src][NT - 1];
}

__global__ __launch_bounds__(256) void k_scan_blocks(
    const int* __restrict__ ghist,  // [NT][BLOCKS_P]
    const int* __restrict__ csum,
    int* __restrict__ goff)         // [NT][BLOCKS_P] per-(bin,block) start slot
{
    const int bin = blockIdx.x * 256 + threadIdx.x;
    if (bin >= NT) return;
    int run = csum[bin];
    const int* row  = ghist + (size_t)bin * BLOCKS_P;
    int*       orow = goff  + (size_t)bin * BLOCKS_P;
    for (int b = 0; b < BLOCKS_P; ++b) { orow[b] = run; run += row[b]; }
}

__global__ __launch_bounds__(256) void k_scatter(
    const float* __restrict__ points,
    const float* __restrict__ offset,
    const float* __restrict__ scaling,
    const int* __restrict__ goff,
    int* __restrict__ perm,
    int n, int ppb)
{
    __shared__ int cur[NT];
    const int b = blockIdx.x;
    for (int i = threadIdx.x; i < NT; i += 256)
        cur[i] = goff[(size_t)i * BLOCKS_P + b];
    __syncthreads();
    const int lo = b * ppb;
    const int hi = min(lo + ppb, n);
    for (int p = lo + threadIdx.x; p < hi; p += 256) {
        int l[3]; float wb[3];
        const int t = point_coords(points, offset, scaling, p, l, wb);
        const int slot = atomicAdd(&cur[t], 1);   // LDS atomic only
        perm[slot] = p;
    }
}

// ---------------- main sampler: persistent, XCD-pinned, L2-windowed ----------------

__global__ __launch_bounds__(256) void k_sample_sorted(
    const int*   __restrict__ perm,
    const int*   __restrict__ csum,
    const float* __restrict__ points,
    const float* __restrict__ data,
    const int*   __restrict__ links,
    const float* __restrict__ offset,
    const float* __restrict__ scaling,
    float*       __restrict__ out)
{
    const int k = blockIdx.x & (NXCD - 1);   // XCD id (round-robin dispatch)
    const int j = blockIdx.x >> 3;           // block idx within XCD [0,128)
    const int lo = csum[k * TPX];
    const int hi = csum[(k + 1) * TPX];
    const int nwork = (hi - lo) * CHUNKS;
    const int stride = (SAMPLE_BLOCKS / NXCD) * 256;   // 32768 items window

    for (int item = j * 256 + (int)threadIdx.x; item < nwork; item += stride) {
        const int slot = lo + item / CHUNKS;
        const int c    = item % CHUNKS;
        const int p    = perm[slot];          // 7 lanes same addr -> broadcast

        int l[3]; float wb[3];
        (void)point_coords(points, offset, scaling, p, l, wb);
        const int gbase = (l[0] * RESO + l[1]) * RESO + l[2];

        const int dz = 1, dy = RESO, dx = RESO * RESO;
        int lk[8];
        lk[0] = links[gbase];
        lk[1] = links[gbase + dz];
        lk[2] = links[gbase + dy];
        lk[3] = links[gbase + dy + dz];
        lk[4] = links[gbase + dx];
        lk[5] = links[gbase + dx + dz];
        lk[6] = links[gbase + dx + dy];
        lk[7] = links[gbase + dx + dy + dz];

        float4 cv[8];
#pragma unroll
        for (int q = 0; q < 8; ++q) {
            const int idx = lk[q] < 0 ? 0 : lk[q];
            cv[q] = *reinterpret_cast<const float4*>(
                data + (size_t)idx * DATA_DIM + (size_t)c * 4);
        }
#pragma unroll
        for (int q = 0; q < 8; ++q)
            if (lk[q] < 0) cv[q] = make_float4(0.f, 0.f, 0.f, 0.f);

        const float waz = 1.0f - wb[2], wbz = wb[2];
        const float way = 1.0f - wb[1], wby = wb[1];
        const float wax = 1.0f - wb[0], wbx = wb[0];

        float4 c00 = f4_lerp(cv[0], cv[1], waz, wbz);
        float4 c01 = f4_lerp(cv[2], cv[3], waz, wbz);
        float4 c10 = f4_lerp(cv[4], cv[5], waz, wbz);
        float4 c11 = f4_lerp(cv[6], cv[7], waz, wbz);

        float4 c0 = f4_lerp(c00, c01, way, wby);
        float4 c1 = f4_lerp(c10, c11, way, wby);
        float4 s  = f4_lerp(c0, c1, wax, wbx);

        *reinterpret_cast<float4*>(out + (size_t)p * DATA_DIM + (size_t)c * 4) = s;
    }
}

// ---------------- fallback: direct order (proven 553 us) ----------------

__global__ __launch_bounds__(256) void k_sample_direct(
    const float* __restrict__ points,
    const float* __restrict__ data,
    const int*   __restrict__ links,
    const float* __restrict__ offset,
    const float* __restrict__ scaling,
    float*       __restrict__ out,
    int n_pts)
{
    const int tid = blockIdx.x * blockDim.x + threadIdx.x;
    const int total = n_pts * CHUNKS;
    if (tid >= total) return;
    const int p = tid / CHUNKS;
    const int c = tid - p * CHUNKS;

    int l[3]; float wb[3];
    (void)point_coords(points, offset, scaling, p, l, wb);
    const int gbase = (l[0] * RESO + l[1]) * RESO + l[2];

    const int dz = 1, dy = RESO, dx = RESO * RESO;
    int lk[8];
    lk[0] = links[gbase];
    lk[1] = links[gbase + dz];
    lk[2] = links[gbase + dy];
    lk[3] = links[gbase + dy + dz];
    lk[4] = links[gbase + dx];
    lk[5] = links[gbase + dx + dz];
    lk[6] = links[gbase + dx + dy];
    lk[7] = links[gbase + dx + dy + dz];

    float4 cv[8];
#pragma unroll
    for (int q = 0; q < 8; ++q) {
        const int idx = lk[q] < 0 ? 0 : lk[q];
        cv[q] = *reinterpret_cast<const float4*>(
            data + (size_t)idx * DATA_DIM + (size_t)c * 4);
    }
#pragma unroll
    for (int q = 0; q < 8; ++q)
        if (lk[q] < 0) cv[q] = make_float4(0.f, 0.f, 0.f, 0.f);

    const float waz = 1.0f - wb[2], wbz = wb[2];
    const float way = 1.0f - wb[1], wby = wb[1];
    const float wax = 1.0f - wb[0], wbx = wb[0];

    float4 c00 = f4_lerp(cv[0], cv[1], waz, wbz);
    float4 c01 = f4_lerp(cv[2], cv[3], waz, wbz);
    float4 c10 = f4_lerp(cv[4], cv[5], waz, wbz);
    float4 c11 = f4_lerp(cv[6], cv[7], waz, wbz);

    float4 c0 = f4_lerp(c00, c01, way, wby);
    float4 c1 = f4_lerp(c10, c11, way, wby);
    float4 s  = f4_lerp(c0, c1, wax, wbx);

    *reinterpret_cast<float4*>(out + (size_t)tid * 4) = s;
}

// ---------------- launch ----------------

extern "C" void kernel_launch(void* const* d_in, const int* in_sizes, int n_in,
                              void* d_out, int out_size, void* d_ws, size_t ws_size,
                              hipStream_t stream)
{
    const float* points  = (const float*)d_in[0];
    const float* data    = (const float*)d_in[1];
    const int*   links   = (const int*)d_in[2];
    const float* offset  = (const float*)d_in[3];
    const float* scaling = (const float*)d_in[4];
    float*       out     = (float*)d_out;

    const int n_pts = in_sizes[0] / 3;

    // ws layout: ghist[NT*BLOCKS_P] | goff[NT*BLOCKS_P] | csum[NT+1] | perm[n]
    size_t off = 0;
    auto alloc = [&](size_t bytes) {
        size_t a = off;
        off = (off + bytes + 255) & ~(size_t)255;
        return a;
    };
    const size_t o_ghist = alloc((size_t)NT * BLOCKS_P * 4);
    const size_t o_goff  = alloc((size_t)NT * BLOCKS_P * 4);
    const size_t o_csum  = alloc((size_t)(NT + 1) * 4);
    const size_t o_perm  = alloc((size_t)n_pts * 4);
    const size_t need = off;

    if (ws_size >= need) {
        int* ghist = (int*)((char*)d_ws + o_ghist);
        int* goff  = (int*)((char*)d_ws + o_goff);
        int* csum  = (int*)((char*)d_ws + o_csum);
        int* perm  = (int*)((char*)d_ws + o_perm);

        const int ppb = (n_pts + BLOCKS_P - 1) / BLOCKS_P;

        k_hist<<<BLOCKS_P, 256, 0, stream>>>(points, offset, scaling, ghist, n_pts, ppb);
        k_scan_bins<<<1, 1024, 0, stream>>>(ghist, csum);
        k_scan_blocks<<<(NT + 255) / 256, 256, 0, stream>>>(ghist, csum, goff);
        k_scatter<<<BLOCKS_P, 256, 0, stream>>>(points, offset, scaling, goff, perm,
                                                n_pts, ppb);
        k_sample_sorted<<<SAMPLE_BLOCKS, 256, 0, stream>>>(
            perm, csum, points, data, links, offset, scaling, out);
    } else {
        const int total = n_pts * CHUNKS;
        k_sample_direct<<<(total + 255) / 256, 256, 0, stream>>>(
            points, data, links, offset, scaling, out, n_pts);
    }
}

// Round 6
// 485.313 us; speedup vs baseline: 1.9315x; 1.1967x over previous
//
#include <hip/hip_runtime.h>
#include <stdint.h>

#define RESO 192
#define DATA_DIM 28
#define CHUNKS 7        // DATA_DIM / 4
#define TPA 12          // tiles per axis (tile = 16 cells)
#define NT 1728         // TPA^3 bins
#define NXCD 8
#define TPX 216         // NT / NXCD -> contiguous x-slab per XCD
#define BLOCKS_P 256    // histogram / scatter blocks

// ---------------- shared device helpers ----------------

__device__ __forceinline__ float4 f4_lerp(float4 a, float4 b, float wa, float wb) {
    float4 r;
    r.x = fmaf(a.x, wa, b.x * wb);
    r.y = fmaf(a.y, wa, b.y * wb);
    r.z = fmaf(a.z, wa, b.z * wb);
    r.w = fmaf(a.w, wa, b.w * wb);
    return r;
}

__device__ __forceinline__ int point_coords(
    const float* __restrict__ points,
    const float* __restrict__ offset,
    const float* __restrict__ scaling,
    int p, int* l, float* wb)
{
    int t = 0;
#pragma unroll
    for (int i = 0; i < 3; ++i) {
        float v = fmaf(points[(size_t)p * 3 + i], scaling[i] * (float)RESO,
                       offset[i] * (float)RESO - 0.5f);
        v = fminf(fmaxf(v, 0.0f), (float)RESO - 1.0f);
        int li = (int)v;                 // v >= 0 -> trunc == floor
        if (li > RESO - 2) li = RESO - 2;
        l[i] = li;
        wb[i] = v - (float)li;
        t = t * TPA + (li >> 4);         // tile = 16 cells
    }
    return t;
}

// ---------------- sort pipeline (global-atomic-free) ----------------

__global__ __launch_bounds__(256) void k_hist(
    const float* __restrict__ points,
    const float* __restrict__ offset,
    const float* __restrict__ scaling,
    int* __restrict__ ghist,   // [NT][BLOCKS_P]
    int n, int ppb)
{
    __shared__ int lh[NT];
    for (int i = threadIdx.x; i < NT; i += 256) lh[i] = 0;
    __syncthreads();
    const int b = blockIdx.x;
    const int lo = b * ppb;
    const int hi = min(lo + ppb, n);
    for (int p = lo + threadIdx.x; p < hi; p += 256) {
        int l[3]; float wb[3];
        const int t = point_coords(points, offset, scaling, p, l, wb);
        atomicAdd(&lh[t], 1);
    }
    __syncthreads();
    for (int i = threadIdx.x; i < NT; i += 256)
        ghist[(size_t)i * BLOCKS_P + b] = lh[i];
}

// one wave per bin: sum its BLOCKS_P row
__global__ __launch_bounds__(256) void k_rowsum(
    const int* __restrict__ ghist,   // [NT][BLOCKS_P]
    int* __restrict__ binsum)        // [NT]
{
    const int wave = (blockIdx.x * 256 + threadIdx.x) >> 6;
    const int lane = threadIdx.x & 63;
    if (wave >= NT) return;
    const int* row = ghist + (size_t)wave * BLOCKS_P;
    int s = 0;
#pragma unroll
    for (int i = 0; i < BLOCKS_P / 64; ++i) s += row[lane + i * 64];
#pragma unroll
    for (int d = 32; d > 0; d >>= 1) s += __shfl_xor(s, d, 64);
    if (lane == 0) binsum[wave] = s;
}

__global__ __launch_bounds__(1024) void k_scan_bins(
    const int* __restrict__ binsum,  // [NT]
    int* __restrict__ csum)          // [NT+1] exclusive bin starts
{
    __shared__ int buf[2][2048];
    for (int t = threadIdx.x; t < 2048; t += 1024)
        buf[0][t] = (t < NT) ? binsum[t] : 0;
    __syncthreads();
    int src = 0;
    for (int d = 1; d < 2048; d <<= 1) {
        for (int t = threadIdx.x; t < 2048; t += 1024)
            buf[src ^ 1][t] = buf[src][t] + (t >= d ? buf[src][t - d] : 0);
        __syncthreads();
        src ^= 1;
    }
    for (int t = threadIdx.x; t < NT; t += 1024)
        csum[t] = t ? buf[src][t - 1] : 0;
    if (threadIdx.x == 0) csum[NT] = buf[src][NT - 1];
}

// one wave per bin: exclusive scan over its BLOCKS_P row, + csum[bin] base
__global__ __launch_bounds__(256) void k_scan_blocks(
    const int* __restrict__ ghist,   // [NT][BLOCKS_P]
    const int* __restrict__ csum,
    int* __restrict__ goff)          // [NT][BLOCKS_P]
{
    const int wave = (blockIdx.x * 256 + threadIdx.x) >> 6;
    const int lane = threadIdx.x & 63;
    if (wave >= NT) return;
    const int* row  = ghist + (size_t)wave * BLOCKS_P;
    int*       orow = goff  + (size_t)wave * BLOCKS_P;
    const int C = BLOCKS_P / 64;   // 4 consecutive entries per lane
    int v[C], pre[C];
    int lsum = 0;
#pragma unroll
    for (int i = 0; i < C; ++i) {
        v[i] = row[lane * C + i];
        pre[i] = lsum;
        lsum += v[i];
    }
    int incl = lsum;
#pragma unroll
    for (int d = 1; d < 64; d <<= 1) {
        int t = __shfl_up(incl, d, 64);
        if (lane >= d) incl += t;
    }
    const int excl = incl - lsum + csum[wave];
#pragma unroll
    for (int i = 0; i < C; ++i)
        orow[lane * C + i] = excl + pre[i];
}

__global__ __launch_bounds__(256) void k_scatter(
    const float* __restrict__ points,
    const float* __restrict__ offset,
    const float* __restrict__ scaling,
    const int* __restrict__ goff,
    int* __restrict__ perm,
    int n, int ppb)
{
    __shared__ int cur[NT];
    const int b = blockIdx.x;
    for (int i = threadIdx.x; i < NT; i += 256)
        cur[i] = goff[(size_t)i * BLOCKS_P + b];
    __syncthreads();
    const int lo = b * ppb;
    const int hi = min(lo + ppb, n);
    for (int p = lo + threadIdx.x; p < hi; p += 256) {
        int l[3]; float wb[3];
        const int t = point_coords(points, offset, scaling, p, l, wb);
        const int slot = atomicAdd(&cur[t], 1);   // LDS atomic only
        perm[slot] = p;
    }
}

// ---------------- main sampler: flat grid + per-XCD grid-stride tail ----------------

__global__ __launch_bounds__(256) void k_sample_sorted(
    const int*   __restrict__ perm,
    const int*   __restrict__ csum,
    const float* __restrict__ points,
    const float* __restrict__ data,
    const int*   __restrict__ links,
    const float* __restrict__ offset,
    const float* __restrict__ scaling,
    float*       __restrict__ out,
    int bpx)
{
    const int k = blockIdx.x & (NXCD - 1);   // XCD id (round-robin dispatch)
    const int j = blockIdx.x >> 3;           // sequential within XCD [0,bpx)
    const int lo = csum[k * TPX];
    const int hi = csum[(k + 1) * TPX];
    const int nwork = (hi - lo) * CHUNKS;
    const int stride = bpx * 256;            // one full pass of this XCD's blocks

    // grid-stride within the XCD range: covers ANY slab imbalance (R5 bugfix);
    // typical block runs exactly one iteration.
    for (int item = j * 256 + (int)threadIdx.x; item < nwork; item += stride) {
        const int slot = lo + item / CHUNKS;
        const int c    = item % CHUNKS;
        const int p    = perm[slot];         // 7 lanes same addr -> broadcast

        int l[3]; float wb[3];
        (void)point_coords(points, offset, scaling, p, l, wb);
        const int gbase = (l[0] * RESO + l[1]) * RESO + l[2];

        const int dz = 1, dy = RESO, dx = RESO * RESO;
        int lk[8];
        lk[0] = links[gbase];
        lk[1] = links[gbase + dz];
        lk[2] = links[gbase + dy];
        lk[3] = links[gbase + dy + dz];
        lk[4] = links[gbase + dx];
        lk[5] = links[gbase + dx + dz];
        lk[6] = links[gbase + dx + dy];
        lk[7] = links[gbase + dx + dy + dz];

        float4 cv[8];
#pragma unroll
        for (int q = 0; q < 8; ++q) {
            const int idx = lk[q] < 0 ? 0 : lk[q];
            cv[q] = *reinterpret_cast<const float4*>(
                data + (size_t)idx * DATA_DIM + (size_t)c * 4);
        }
#pragma unroll
        for (int q = 0; q < 8; ++q)
            if (lk[q] < 0) cv[q] = make_float4(0.f, 0.f, 0.f, 0.f);

        const float waz = 1.0f - wb[2], wbz = wb[2];
        const float way = 1.0f - wb[1], wby = wb[1];
        const float wax = 1.0f - wb[0], wbx = wb[0];

        float4 c00 = f4_lerp(cv[0], cv[1], waz, wbz);
        float4 c01 = f4_lerp(cv[2], cv[3], waz, wbz);
        float4 c10 = f4_lerp(cv[4], cv[5], waz, wbz);
        float4 c11 = f4_lerp(cv[6], cv[7], waz, wbz);

        float4 c0 = f4_lerp(c00, c01, way, wby);
        float4 c1 = f4_lerp(c10, c11, way, wby);
        float4 s  = f4_lerp(c0, c1, wax, wbx);

        *reinterpret_cast<float4*>(out + (size_t)p * DATA_DIM + (size_t)c * 4) = s;
    }
}

// ---------------- fallback: direct order (proven 553 us) ----------------

__global__ __launch_bounds__(256) void k_sample_direct(
    const float* __restrict__ points,
    const float* __restrict__ data,
    const int*   __restrict__ links,
    const float* __restrict__ offset,
    const float* __restrict__ scaling,
    float*       __restrict__ out,
    int n_pts)
{
    const int tid = blockIdx.x * blockDim.x + threadIdx.x;
    const int total = n_pts * CHUNKS;
    if (tid >= total) return;
    const int p = tid / CHUNKS;
    const int c = tid - p * CHUNKS;

    int l[3]; float wb[3];
    (void)point_coords(points, offset, scaling, p, l, wb);
    const int gbase = (l[0] * RESO + l[1]) * RESO + l[2];

    const int dz = 1, dy = RESO, dx = RESO * RESO;
    int lk[8];
    lk[0] = links[gbase];
    lk[1] = links[gbase + dz];
    lk[2] = links[gbase + dy];
    lk[3] = links[gbase + dy + dz];
    lk[4] = links[gbase + dx];
    lk[5] = links[gbase + dx + dz];
    lk[6] = links[gbase + dx + dy];
    lk[7] = links[gbase + dx + dy + dz];

    float4 cv[8];
#pragma unroll
    for (int q = 0; q < 8; ++q) {
        const int idx = lk[q] < 0 ? 0 : lk[q];
        cv[q] = *reinterpret_cast<const float4*>(
            data + (size_t)idx * DATA_DIM + (size_t)c * 4);
    }
#pragma unroll
    for (int q = 0; q < 8; ++q)
        if (lk[q] < 0) cv[q] = make_float4(0.f, 0.f, 0.f, 0.f);

    const float waz = 1.0f - wb[2], wbz = wb[2];
    const float way = 1.0f - wb[1], wby = wb[1];
    const float wax = 1.0f - wb[0], wbx = wb[0];

    float4 c00 = f4_lerp(cv[0], cv[1], waz, wbz);
    float4 c01 = f4_lerp(cv[2], cv[3], waz, wbz);
    float4 c10 = f4_lerp(cv[4], cv[5], waz, wbz);
    float4 c11 = f4_lerp(cv[6], cv[7], waz, wbz);

    float4 c0 = f4_lerp(c00, c01, way, wby);
    float4 c1 = f4_lerp(c10, c11, way, wby);
    float4 s  = f4_lerp(c0, c1, wax, wbx);

    *reinterpret_cast<float4*>(out + (size_t)tid * 4) = s;
}

// ---------------- launch ----------------

extern "C" void kernel_launch(void* const* d_in, const int* in_sizes, int n_in,
                              void* d_out, int out_size, void* d_ws, size_t ws_size,
                              hipStream_t stream)
{
    const float* points  = (const float*)d_in[0];
    const float* data    = (const float*)d_in[1];
    const int*   links   = (const int*)d_in[2];
    const float* offset  = (const float*)d_in[3];
    const float* scaling = (const float*)d_in[4];
    float*       out     = (float*)d_out;

    const int n_pts = in_sizes[0] / 3;

    // ws layout: ghist | goff | binsum | csum | perm
    size_t off = 0;
    auto alloc = [&](size_t bytes) {
        size_t a = off;
        off = (off + bytes + 255) & ~(size_t)255;
        return a;
    };
    const size_t o_ghist  = alloc((size_t)NT * BLOCKS_P * 4);
    const size_t o_goff   = alloc((size_t)NT * BLOCKS_P * 4);
    const size_t o_binsum = alloc((size_t)NT * 4);
    const size_t o_csum   = alloc((size_t)(NT + 1) * 4);
    const size_t o_perm   = alloc((size_t)n_pts * 4);
    const size_t need = off;

    if (ws_size >= need) {
        int* ghist  = (int*)((char*)d_ws + o_ghist);
        int* goff   = (int*)((char*)d_ws + o_goff);
        int* binsum = (int*)((char*)d_ws + o_binsum);
        int* csum   = (int*)((char*)d_ws + o_csum);
        int* perm   = (int*)((char*)d_ws + o_perm);

        const int ppb = (n_pts + BLOCKS_P - 1) / BLOCKS_P;

        k_hist<<<BLOCKS_P, 256, 0, stream>>>(points, offset, scaling, ghist, n_pts, ppb);
        k_rowsum<<<(NT * 64 + 255) / 256, 256, 0, stream>>>(ghist, binsum);
        k_scan_bins<<<1, 1024, 0, stream>>>(binsum, csum);
        k_scan_blocks<<<(NT * 64 + 255) / 256, 256, 0, stream>>>(ghist, csum, goff);
        k_scatter<<<BLOCKS_P, 256, 0, stream>>>(points, offset, scaling, goff, perm,
                                                n_pts, ppb);

        // flat grid sized for the AVERAGE slab; grid-stride loop absorbs the
        // deterministic edge-slab imbalance (~+2.5%) safely.
        const long long items_per_xcd =
            ((long long)n_pts * CHUNKS + NXCD - 1) / NXCD;
        const int bpx = (int)((items_per_xcd + 255) / 256);
        k_sample_sorted<<<bpx * NXCD, 256, 0, stream>>>(
            perm, csum, points, data, links, offset, scaling, out, bpx);
    } else {
        const int total = n_pts * CHUNKS;
        k_sample_direct<<<(total + 255) / 256, 256, 0, stream>>>(
            points, data, links, offset, scaling, out, n_pts);
    }
}

// Round 7
// 443.194 us; speedup vs baseline: 2.1151x; 1.0950x over previous
//
#include <hip/hip_runtime.h>
#include <stdint.h>

#define RESO 192
#define NVOX (RESO * RESO * RESO)
#define DATA_DIM 28
#define CHUNKS 7        // DATA_DIM / 4
#define TPA 12          // tiles per axis (tile = 16 cells)
#define NT 1728         // TPA^3 bins
#define NXCD 8
#define TPX 216         // NT / NXCD -> contiguous x-slab per XCD
#define BLOCKS_P 256    // histogram / scatter blocks

// ---------------- shared device helpers ----------------

__device__ __forceinline__ float4 f4_lerp(float4 a, float4 b, float wa, float wb) {
    float4 r;
    r.x = fmaf(a.x, wa, b.x * wb);
    r.y = fmaf(a.y, wa, b.y * wb);
    r.z = fmaf(a.z, wa, b.z * wb);
    r.w = fmaf(a.w, wa, b.w * wb);
    return r;
}

__device__ __forceinline__ int point_coords(
    const float* __restrict__ points,
    const float* __restrict__ offset,
    const float* __restrict__ scaling,
    int p, int* l, float* wb)
{
    int t = 0;
#pragma unroll
    for (int i = 0; i < 3; ++i) {
        float v = fmaf(points[(size_t)p * 3 + i], scaling[i] * (float)RESO,
                       offset[i] * (float)RESO - 0.5f);
        v = fminf(fmaxf(v, 0.0f), (float)RESO - 1.0f);
        int li = (int)v;                 // v >= 0 -> trunc == floor
        if (li > RESO - 2) li = RESO - 2;
        l[i] = li;
        wb[i] = v - (float)li;
        t = t * TPA + (li >> 4);         // tile = 16 cells
    }
    return t;
}

// ---------------- links == arange detector ----------------

__global__ void k_init_flag(int* __restrict__ flag) {
    if (threadIdx.x == 0) flag[0] = 1;
}

__global__ __launch_bounds__(256) void k_check_links(
    const int* __restrict__ links, int* __restrict__ flag)
{
    bool ok = true;
    for (int i = blockIdx.x * 256 + threadIdx.x; i < NVOX; i += gridDim.x * 256)
        ok &= (links[i] == i);
    if (!ok) atomicAnd(flag, 0);   // never executes for identity links
}

// ---------------- sort pipeline (global-atomic-free) ----------------

__global__ __launch_bounds__(256) void k_hist(
    const float* __restrict__ points,
    const float* __restrict__ offset,
    const float* __restrict__ scaling,
    int* __restrict__ ghist,   // [NT][BLOCKS_P]
    int n, int ppb)
{
    __shared__ int lh[NT];
    for (int i = threadIdx.x; i < NT; i += 256) lh[i] = 0;
    __syncthreads();
    const int b = blockIdx.x;
    const int lo = b * ppb;
    const int hi = min(lo + ppb, n);
    for (int p = lo + threadIdx.x; p < hi; p += 256) {
        int l[3]; float wb[3];
        const int t = point_coords(points, offset, scaling, p, l, wb);
        atomicAdd(&lh[t], 1);
    }
    __syncthreads();
    for (int i = threadIdx.x; i < NT; i += 256)
        ghist[(size_t)i * BLOCKS_P + b] = lh[i];
}

__global__ __launch_bounds__(256) void k_rowsum(
    const int* __restrict__ ghist, int* __restrict__ binsum)
{
    const int wave = (blockIdx.x * 256 + threadIdx.x) >> 6;
    const int lane = threadIdx.x & 63;
    if (wave >= NT) return;
    const int* row = ghist + (size_t)wave * BLOCKS_P;
    int s = 0;
#pragma unroll
    for (int i = 0; i < BLOCKS_P / 64; ++i) s += row[lane + i * 64];
#pragma unroll
    for (int d = 32; d > 0; d >>= 1) s += __shfl_xor(s, d, 64);
    if (lane == 0) binsum[wave] = s;
}

__global__ __launch_bounds__(1024) void k_scan_bins(
    const int* __restrict__ binsum, int* __restrict__ csum)
{
    __shared__ int buf[2][2048];
    for (int t = threadIdx.x; t < 2048; t += 1024)
        buf[0][t] = (t < NT) ? binsum[t] : 0;
    __syncthreads();
    int src = 0;
    for (int d = 1; d < 2048; d <<= 1) {
        for (int t = threadIdx.x; t < 2048; t += 1024)
            buf[src ^ 1][t] = buf[src][t] + (t >= d ? buf[src][t - d] : 0);
        __syncthreads();
        src ^= 1;
    }
    for (int t = threadIdx.x; t < NT; t += 1024)
        csum[t] = t ? buf[src][t - 1] : 0;
    if (threadIdx.x == 0) csum[NT] = buf[src][NT - 1];
}

__global__ __launch_bounds__(256) void k_scan_blocks(
    const int* __restrict__ ghist,
    const int* __restrict__ csum,
    int* __restrict__ goff)
{
    const int wave = (blockIdx.x * 256 + threadIdx.x) >> 6;
    const int lane = threadIdx.x & 63;
    if (wave >= NT) return;
    const int* row  = ghist + (size_t)wave * BLOCKS_P;
    int*       orow = goff  + (size_t)wave * BLOCKS_P;
    const int C = BLOCKS_P / 64;
    int v[C], pre[C];
    int lsum = 0;
#pragma unroll
    for (int i = 0; i < C; ++i) {
        v[i] = row[lane * C + i];
        pre[i] = lsum;
        lsum += v[i];
    }
    int incl = lsum;
#pragma unroll
    for (int d = 1; d < 64; d <<= 1) {
        int t = __shfl_up(incl, d, 64);
        if (lane >= d) incl += t;
    }
    const int excl = incl - lsum + csum[wave];
#pragma unroll
    for (int i = 0; i < C; ++i)
        orow[lane * C + i] = excl + pre[i];
}

// scatter: also materializes the 16B {wb, gbase} payload (sampler reads this,
// not points) so the sampler's coord math + 3 point loads disappear.
__global__ __launch_bounds__(256) void k_scatter(
    const float* __restrict__ points,
    const float* __restrict__ offset,
    const float* __restrict__ scaling,
    const int* __restrict__ goff,
    int* __restrict__ perm,
    float4* __restrict__ pre4,
    int n, int ppb)
{
    __shared__ int cur[NT];
    const int b = blockIdx.x;
    for (int i = threadIdx.x; i < NT; i += 256)
        cur[i] = goff[(size_t)i * BLOCKS_P + b];
    __syncthreads();
    const int lo = b * ppb;
    const int hi = min(lo + ppb, n);
    for (int p = lo + threadIdx.x; p < hi; p += 256) {
        int l[3]; float wb[3];
        const int t = point_coords(points, offset, scaling, p, l, wb);
        const int slot = atomicAdd(&cur[t], 1);   // LDS atomic only
        const int gbase = (l[0] * RESO + l[1]) * RESO + l[2];
        perm[slot] = p;
        pre4[slot] = make_float4(wb[0], wb[1], wb[2], __int_as_float(gbase));
    }
}

// ---------------- main sampler: flat grid + per-XCD grid-stride ----------------

__global__ __launch_bounds__(256) void k_sample_sorted(
    const int*    __restrict__ perm,
    const float4* __restrict__ pre4,
    const int*    __restrict__ csum,
    const float*  __restrict__ data,
    const int*    __restrict__ links,
    const int*    __restrict__ flag,
    float*        __restrict__ out,
    int bpx)
{
    const int k = blockIdx.x & (NXCD - 1);   // XCD id (round-robin dispatch)
    const int j = blockIdx.x >> 3;
    const int lo = csum[k * TPX];
    const int hi = csum[(k + 1) * TPX];
    const int nwork = (hi - lo) * CHUNKS;
    const int stride = bpx * 256;
    const bool fast = (flag[0] != 0);        // uniform scalar branch

    for (int item = j * 256 + (int)threadIdx.x; item < nwork; item += stride) {
        const int slot = lo + item / CHUNKS;
        const int c    = item % CHUNKS;
        const int p    = perm[slot];         // broadcast across 7 chunk-lanes
        const float4 pw = pre4[slot];        // broadcast
        const int gbase = __float_as_int(pw.w);

        const int dz = 1, dy = RESO, dx = RESO * RESO;
        float4 cv[8];

        if (fast) {
            // links == arange: row index == node index, all links >= 0.
            const int off[8] = {0, dz, dy, dy + dz, dx, dx + dz, dx + dy, dx + dy + dz};
#pragma unroll
            for (int q = 0; q < 8; ++q) {
                cv[q] = *reinterpret_cast<const float4*>(
                    data + (size_t)(gbase + off[q]) * DATA_DIM + (size_t)c * 4);
            }
        } else {
            int lk[8];
            lk[0] = links[gbase];
            lk[1] = links[gbase + dz];
            lk[2] = links[gbase + dy];
            lk[3] = links[gbase + dy + dz];
            lk[4] = links[gbase + dx];
            lk[5] = links[gbase + dx + dz];
            lk[6] = links[gbase + dx + dy];
            lk[7] = links[gbase + dx + dy + dz];
#pragma unroll
            for (int q = 0; q < 8; ++q) {
                const int idx = lk[q] < 0 ? 0 : lk[q];
                cv[q] = *reinterpret_cast<const float4*>(
                    data + (size_t)idx * DATA_DIM + (size_t)c * 4);
            }
#pragma unroll
            for (int q = 0; q < 8; ++q)
                if (lk[q] < 0) cv[q] = make_float4(0.f, 0.f, 0.f, 0.f);
        }

        const float waz = 1.0f - pw.z, wbz = pw.z;
        const float way = 1.0f - pw.y, wby = pw.y;
        const float wax = 1.0f - pw.x, wbx = pw.x;

        float4 c00 = f4_lerp(cv[0], cv[1], waz, wbz);
        float4 c01 = f4_lerp(cv[2], cv[3], waz, wbz);
        float4 c10 = f4_lerp(cv[4], cv[5], waz, wbz);
        float4 c11 = f4_lerp(cv[6], cv[7], waz, wbz);

        float4 c0 = f4_lerp(c00, c01, way, wby);
        float4 c1 = f4_lerp(c10, c11, way, wby);
        float4 s  = f4_lerp(c0, c1, wax, wbx);

        *reinterpret_cast<float4*>(out + (size_t)p * DATA_DIM + (size_t)c * 4) = s;
    }
}

// ---------------- fallback: direct order ----------------

__global__ __launch_bounds__(256) void k_sample_direct(
    const float* __restrict__ points,
    const float* __restrict__ data,
    const int*   __restrict__ links,
    const float* __restrict__ offset,
    const float* __restrict__ scaling,
    float*       __restrict__ out,
    int n_pts)
{
    const int tid = blockIdx.x * blockDim.x + threadIdx.x;
    const int total = n_pts * CHUNKS;
    if (tid >= total) return;
    const int p = tid / CHUNKS;
    const int c = tid - p * CHUNKS;

    int l[3]; float wb[3];
    (void)point_coords(points, offset, scaling, p, l, wb);
    const int gbase = (l[0] * RESO + l[1]) * RESO + l[2];

    const int dz = 1, dy = RESO, dx = RESO * RESO;
    int lk[8];
    lk[0] = links[gbase];
    lk[1] = links[gbase + dz];
    lk[2] = links[gbase + dy];
    lk[3] = links[gbase + dy + dz];
    lk[4] = links[gbase + dx];
    lk[5] = links[gbase + dx + dz];
    lk[6] = links[gbase + dx + dy];
    lk[7] = links[gbase + dx + dy + dz];

    float4 cv[8];
#pragma unroll
    for (int q = 0; q < 8; ++q) {
        const int idx = lk[q] < 0 ? 0 : lk[q];
        cv[q] = *reinterpret_cast<const float4*>(
            data + (size_t)idx * DATA_DIM + (size_t)c * 4);
    }
#pragma unroll
    for (int q = 0; q < 8; ++q)
        if (lk[q] < 0) cv[q] = make_float4(0.f, 0.f, 0.f, 0.f);

    const float waz = 1.0f - wb[2], wbz = wb[2];
    const float way = 1.0f - wb[1], wby = wb[1];
    const float wax = 1.0f - wb[0], wbx = wb[0];

    float4 c00 = f4_lerp(cv[0], cv[1], waz, wbz);
    float4 c01 = f4_lerp(cv[2], cv[3], waz, wbz);
    float4 c10 = f4_lerp(cv[4], cv[5], waz, wbz);
    float4 c11 = f4_lerp(cv[6], cv[7], waz, wbz);

    float4 c0 = f4_lerp(c00, c01, way, wby);
    float4 c1 = f4_lerp(c10, c11, way, wby);
    float4 s  = f4_lerp(c0, c1, wax, wbx);

    *reinterpret_cast<float4*>(out + (size_t)tid * 4) = s;
}

// ---------------- launch ----------------

extern "C" void kernel_launch(void* const* d_in, const int* in_sizes, int n_in,
                              void* d_out, int out_size, void* d_ws, size_t ws_size,
                              hipStream_t stream)
{
    const float* points  = (const float*)d_in[0];
    const float* data    = (const float*)d_in[1];
    const int*   links   = (const int*)d_in[2];
    const float* offset  = (const float*)d_in[3];
    const float* scaling = (const float*)d_in[4];
    float*       out     = (float*)d_out;

    const int n_pts = in_sizes[0] / 3;

    // ws layout: flag | ghist | goff | binsum | csum | perm | pre4
    size_t off = 0;
    auto alloc = [&](size_t bytes) {
        size_t a = off;
        off = (off + bytes + 255) & ~(size_t)255;
        return a;
    };
    const size_t o_flag   = alloc(4);
    const size_t o_ghist  = alloc((size_t)NT * BLOCKS_P * 4);
    const size_t o_goff   = alloc((size_t)NT * BLOCKS_P * 4);
    const size_t o_binsum = alloc((size_t)NT * 4);
    const size_t o_csum   = alloc((size_t)(NT + 1) * 4);
    const size_t o_perm   = alloc((size_t)n_pts * 4);
    const size_t o_pre4   = alloc((size_t)n_pts * 16);
    const size_t need = off;

    if (ws_size >= need) {
        int*    flag   = (int*)((char*)d_ws + o_flag);
        int*    ghist  = (int*)((char*)d_ws + o_ghist);
        int*    goff   = (int*)((char*)d_ws + o_goff);
        int*    binsum = (int*)((char*)d_ws + o_binsum);
        int*    csum   = (int*)((char*)d_ws + o_csum);
        int*    perm   = (int*)((char*)d_ws + o_perm);
        float4* pre4   = (float4*)((char*)d_ws + o_pre4);

        const int ppb = (n_pts + BLOCKS_P - 1) / BLOCKS_P;

        k_init_flag<<<1, 64, 0, stream>>>(flag);
        k_check_links<<<2048, 256, 0, stream>>>(links, flag);
        k_hist<<<BLOCKS_P, 256, 0, stream>>>(points, offset, scaling, ghist, n_pts, ppb);
        k_rowsum<<<(NT * 64 + 255) / 256, 256, 0, stream>>>(ghist, binsum);
        k_scan_bins<<<1, 1024, 0, stream>>>(binsum, csum);
        k_scan_blocks<<<(NT * 64 + 255) / 256, 256, 0, stream>>>(ghist, csum, goff);
        k_scatter<<<BLOCKS_P, 256, 0, stream>>>(points, offset, scaling, goff,
                                                perm, pre4, n_pts, ppb);

        const long long items_per_xcd =
            ((long long)n_pts * CHUNKS + NXCD - 1) / NXCD;
        const int bpx = (int)((items_per_xcd + 255) / 256);
        k_sample_sorted<<<bpx * NXCD, 256, 0, stream>>>(
            perm, pre4, csum, data, links, flag, out, bpx);
    } else {
        const int total = n_pts * CHUNKS;
        k_sample_direct<<<(total + 255) / 256, 256, 0, stream>>>(
            points, data, links, offset, scaling, out, n_pts);
    }
}